// Round 7
// baseline (137.278 us; speedup 1.0000x reference)
//
#include <hip/hip_runtime.h>
#include <hip/hip_cooperative_groups.h>

namespace cg = cooperative_groups;

#define NN 160      // nodes
#define BB 128      // batch
#define HH 256      // hidden
#define EE 5120     // edges
#define ST 128      // state dim
#define AC 32       // action dim
#define HALF 128    // HH/2

typedef __attribute__((ext_vector_type(8))) short short8;
typedef __attribute__((ext_vector_type(4))) float f32x4;
typedef unsigned short us;

__device__ inline us f2b(float f) {
    unsigned u = __builtin_bit_cast(unsigned, f);
    unsigned r = (u + 0x7FFFu + ((u >> 16) & 1u)) >> 16;
    return (us)r;
}

// ---------- K1: graph rows + P row (int-exact) + weight transposes ----------
__global__ __launch_bounds__(256)
void k_pre(const int* __restrict__ ei, const float* __restrict__ W1,
           const float* __restrict__ W2, float* __restrict__ P,
           us* __restrict__ Mb, us* __restrict__ W1t, us* __restrict__ W2t)
{
    const int bx = blockIdx.x, tid = threadIdx.x;
    if (bx < NN) {
        __shared__ int crow[NN];
        __shared__ unsigned abit[NN * NN / 32];   // 3.2 KB
        __shared__ float invdeg;
        if (tid < NN) crow[tid] = 0;
        for (int i = tid; i < NN * NN / 32; i += 256) abit[i] = 0;
        __syncthreads();
        for (int e = tid; e < EE; e += 256) {
            int s = ei[e], d = ei[EE + e];
            int p = d * NN + s;
            atomicOr(&abit[p >> 5], 1u << (p & 31));
            if (d == bx) atomicAdd(&crow[s], 1);
        }
        if (tid < NN) {
            int p = tid * NN + tid;
            atomicOr(&abit[p >> 5], 1u << (p & 31));
        }
        __syncthreads();
        if (tid == 0) {
            int dg = 0;
            for (int j = 0; j < NN; j++) dg += crow[j];
            invdeg = 1.0f / (float)(dg < 1 ? 1 : dg);
        }
        __syncthreads();
        if (tid < NN) {
            int s = 0;
            for (int k = 0; k < NN; k++) {
                int p = k * NN + tid;
                if (abit[p >> 5] & (1u << (p & 31))) s += crow[k];
            }
            P[bx * NN + tid]  = (float)s * invdeg;
            Mb[bx * NN + tid] = f2b((float)crow[tid] * invdeg);
        }
    } else if (bx < NN + 160) {                   // W1t: 256x160
        int idx = (bx - NN) * 256 + tid;
        int n = idx / NN, k = idx - n * NN;
        W1t[idx] = f2b(W1[k * HH + n]);
    } else {                                      // W2t: 256x256
        int idx = (bx - NN - 160) * 256 + tid;
        int n = idx >> 8, k = idx & 255;
        W2t[idx] = f2b(W2[k * HH + n]);
    }
}

// ---------- K2 (cooperative): phase A l1+agg2 -> t; grid sync; phase B mm2+pool+head
// grid (2, BB) = 256 blocks, 256 threads (4 waves 2x2)
__global__ __launch_bounds__(256)
void k_fused(const float* __restrict__ P, const float* __restrict__ state,
             const float* __restrict__ action, const us* __restrict__ W1t,
             const float* __restrict__ b1, const us* __restrict__ Mb,
             const us* __restrict__ W2t, const float* __restrict__ b2,
             const float* __restrict__ Wo, const float* __restrict__ bo,
             us* __restrict__ t_glb, float* __restrict__ out)
{
    constexpr int KS = 40;    // staging K-stride (shorts)
    constexpr int H1S = 168;  // h1 row stride
    __shared__ float xb[NN];
    __shared__ __align__(16) us h1[HALF][H1S];        // 43 KB
    __shared__ __align__(16) us stg[(NN + HALF) * KS];// 23 KB
    __shared__ float pp2[8][HALF];                    // 4 KB
    __shared__ float partials[2][ST];                 // 1 KB
    us* sY  = stg;             // [NN][KS]   GEMM1 Bt
    us* sW  = stg + NN * KS;   // [HALF][KS] GEMM1 A
    us* sM  = stg;             // [NN][KS]   GEMM2 A
    us* sT  = stg;             // [NN][KS]   GEMM3 A
    us* sW2 = stg + NN * KS;   // [HALF][KS] GEMM3 Bt

    const int b = blockIdx.y, ho = blockIdx.x * HALF;
    const int tid = threadIdx.x, lane = tid & 63, w = tid >> 6;
    const int wr = w >> 1, wc = w & 1;
    const int rl = lane & 15, kq = lane >> 4;

    if (tid < NN) xb[tid] = (tid < ST) ? state[b * ST + tid]
                                       : action[b * AC + (tid - ST)];
    if (blockIdx.x == 0 && tid < ST)               // init out for phase-B atomics
        out[b * ST + tid] = state[b * ST + tid] + bo[tid];
    __syncthreads();

    // ---- GEMM1: M=128(h-half), N=160(i), K=160(j). WM=64, WN=80
    {
        f32x4 acc[4][5];
#pragma unroll
        for (int f = 0; f < 4; f++)
#pragma unroll
            for (int j = 0; j < 5; j++) acc[f][j] = f32x4{0.f, 0.f, 0.f, 0.f};

        for (int k0 = 0; k0 < NN; k0 += 32) {
            for (int idx = tid; idx < 512 + 640; idx += 256) {
                if (idx < 512) {              // A: W1t half rows
                    int r = idx >> 2, c = (idx & 3) * 8;
                    *(short8*)&sW[r * KS + c] =
                        *(const short8*)&W1t[(size_t)(ho + r) * NN + k0 + c];
                } else {                      // Bt: Y = bf16(P*x) on the fly
                    int q = idx - 512;
                    int r = q >> 2, c = (q & 3) * 8;
                    const f32x4* p4 = (const f32x4*)&P[r * NN + k0 + c];
                    f32x4 p0 = p4[0], p1 = p4[1];
                    short8 y;
#pragma unroll
                    for (int u = 0; u < 4; u++) {
                        y[u]     = (short)f2b(p0[u] * xb[k0 + c + u]);
                        y[u + 4] = (short)f2b(p1[u] * xb[k0 + c + 4 + u]);
                    }
                    *(short8*)&sY[r * KS + c] = y;
                }
            }
            __syncthreads();
            short8 af[4], bf[5];
#pragma unroll
            for (int f = 0; f < 4; f++)
                af[f] = *(const short8*)&sW[(wr * 64 + f * 16 + rl) * KS + kq * 8];
#pragma unroll
            for (int j = 0; j < 5; j++)
                bf[j] = *(const short8*)&sY[(wc * 80 + j * 16 + rl) * KS + kq * 8];
#pragma unroll
            for (int f = 0; f < 4; f++)
#pragma unroll
                for (int j = 0; j < 5; j++)
                    acc[f][j] = __builtin_amdgcn_mfma_f32_16x16x32_bf16(
                        af[f], bf[j], acc[f][j], 0, 0, 0);
            __syncthreads();
        }
        // epilogue -> h1 (bias+relu); C/D: col=rl, row=kq*4+reg
#pragma unroll
        for (int f = 0; f < 4; f++) {
            int rowb = wr * 64 + f * 16 + kq * 4;
#pragma unroll
            for (int j = 0; j < 5; j++) {
                int col = wc * 80 + j * 16 + rl;
#pragma unroll
                for (int r = 0; r < 4; r++) {
                    int row = rowb + r;
                    float v = acc[f][j][r] + b1[ho + row];
                    h1[row][col] = f2b(v > 0.f ? v : 0.f);
                }
            }
        }
    }
    __syncthreads();

    // ---- GEMM2: M=160(i), N=128(h-half), K=160(k). WM=80, WN=64 -> global t
    {
        f32x4 acc[5][4];
#pragma unroll
        for (int f = 0; f < 5; f++)
#pragma unroll
            for (int j = 0; j < 4; j++) acc[f][j] = f32x4{0.f, 0.f, 0.f, 0.f};

        for (int k0 = 0; k0 < NN; k0 += 32) {
            for (int idx = tid; idx < 640; idx += 256) {
                int r = idx >> 2, c = (idx & 3) * 8;
                *(short8*)&sM[r * KS + c] =
                    *(const short8*)&Mb[(size_t)r * NN + k0 + c];
            }
            __syncthreads();
            short8 af[5], bf[4];
#pragma unroll
            for (int f = 0; f < 5; f++)
                af[f] = *(const short8*)&sM[(wr * 80 + f * 16 + rl) * KS + kq * 8];
#pragma unroll
            for (int j = 0; j < 4; j++)
                bf[j] = *(const short8*)&h1[wc * 64 + j * 16 + rl][k0 + kq * 8];
#pragma unroll
            for (int f = 0; f < 5; f++)
#pragma unroll
                for (int j = 0; j < 4; j++)
                    acc[f][j] = __builtin_amdgcn_mfma_f32_16x16x32_bf16(
                        af[f], bf[j], acc[f][j], 0, 0, 0);
            __syncthreads();
        }
#pragma unroll
        for (int f = 0; f < 5; f++) {
            int rowb = wr * 80 + f * 16 + kq * 4;
#pragma unroll
            for (int j = 0; j < 4; j++) {
                int col = ho + wc * 64 + j * 16 + rl;
#pragma unroll
                for (int r = 0; r < 4; r++)
                    t_glb[((size_t)b * NN + rowb + r) * HH + col] = f2b(acc[f][j][r]);
            }
        }
    }

    __threadfence();             // device-scope: make t visible across XCDs
    cg::this_grid().sync();

    // ---- Phase B: block = (h'-half p, b). GEMM3: M=160(i), N=128, K=256
    {
        const int ho2 = blockIdx.x * HALF;
        f32x4 acc[5][4];
#pragma unroll
        for (int f = 0; f < 5; f++)
#pragma unroll
            for (int j = 0; j < 4; j++) acc[f][j] = f32x4{0.f, 0.f, 0.f, 0.f};

        for (int k0 = 0; k0 < HH; k0 += 32) {
            for (int idx = tid; idx < 640 + 512; idx += 256) {
                if (idx < 640) {                  // A: t rows
                    int r = idx >> 2, c = (idx & 3) * 8;
                    *(short8*)&sT[r * KS + c] =
                        *(const short8*)&t_glb[((size_t)b * NN + r) * HH + k0 + c];
                } else {                          // Bt: W2t half rows
                    int q = idx - 640;
                    int r = q >> 2, c = (q & 3) * 8;
                    *(short8*)&sW2[r * KS + c] =
                        *(const short8*)&W2t[(size_t)(ho2 + r) * HH + k0 + c];
                }
            }
            __syncthreads();
            short8 af[5], bf[4];
#pragma unroll
            for (int f = 0; f < 5; f++)
                af[f] = *(const short8*)&sT[(wr * 80 + f * 16 + rl) * KS + kq * 8];
#pragma unroll
            for (int j = 0; j < 4; j++)
                bf[j] = *(const short8*)&sW2[(wc * 64 + j * 16 + rl) * KS + kq * 8];
#pragma unroll
            for (int f = 0; f < 5; f++)
#pragma unroll
                for (int j = 0; j < 4; j++)
                    acc[f][j] = __builtin_amdgcn_mfma_f32_16x16x32_bf16(
                        af[f], bf[j], acc[f][j], 0, 0, 0);
            __syncthreads();
        }
        // epilogue: bias+relu, in-lane row sums, slotted store (deterministic)
        const int slot = wr * 4 + kq;
#pragma unroll
        for (int j = 0; j < 4; j++) {
            int lc = wc * 64 + j * 16 + rl;
            float bias = b2[ho2 + lc];
            float s = 0.f;
#pragma unroll
            for (int f = 0; f < 5; f++)
#pragma unroll
                for (int r = 0; r < 4; r++) {
                    float v = acc[f][j][r] + bias;
                    s += v > 0.f ? v : 0.f;
                }
            pp2[slot][lc] = s;
        }
        __syncthreads();
        // head partial over this half's 128 h values
        const int q = tid >> 7, s = tid & 127;
        float part = 0.f;
        for (int lc = q * 64; lc < q * 64 + 64; lc++) {
            float pk = pp2[0][lc] + pp2[1][lc] + pp2[2][lc] + pp2[3][lc]
                     + pp2[4][lc] + pp2[5][lc] + pp2[6][lc] + pp2[7][lc];
            part += pk * Wo[(ho2 + lc) * ST + s];
        }
        partials[q][s] = part;
        __syncthreads();
        if (tid < ST)
            atomicAdd(&out[b * ST + tid],
                      (partials[0][tid] + partials[1][tid]) * (1.0f / NN));
    }
}

extern "C" void kernel_launch(void* const* d_in, const int* in_sizes, int n_in,
                              void* d_out, int out_size, void* d_ws, size_t ws_size,
                              hipStream_t stream) {
    const float* state  = (const float*)d_in[0];
    const float* action = (const float*)d_in[1];
    const int*   ei     = (const int*)d_in[2];
    const float* W1     = (const float*)d_in[3];
    const float* b1     = (const float*)d_in[4];
    const float* W2     = (const float*)d_in[5];
    const float* b2     = (const float*)d_in[6];
    const float* Wo     = (const float*)d_in[7];
    const float* bo     = (const float*)d_in[8];
    float* out = (float*)d_out;

    char* ws = (char*)d_ws;
    size_t off = 0;
    auto alloc = [&](size_t bytes) {
        void* p = ws + off;
        off += (bytes + 255) & ~(size_t)255;
        return p;
    };
    float* P   = (float*)alloc(NN * NN * 4);
    us* Mb  = (us*)alloc(NN * NN * 2);
    us* W1t = (us*)alloc((size_t)HH * NN * 2);
    us* W2t = (us*)alloc((size_t)HH * HH * 2);
    us* t   = (us*)alloc((size_t)BB * NN * HH * 2);

    k_pre<<<NN + 160 + 256, 256, 0, stream>>>(ei, W1, W2, P, Mb, W1t, W2t);

    void* args[] = {
        (void*)&P, (void*)&state, (void*)&action, (void*)&W1t, (void*)&b1,
        (void*)&Mb, (void*)&W2t, (void*)&b2, (void*)&Wo, (void*)&bo,
        (void*)&t, (void*)&out
    };
    hipLaunchCooperativeKernel((const void*)k_fused, dim3(2, BB), dim3(256),
                               args, 0, stream);
}

// Round 9
// 43.679 us; speedup vs baseline: 3.1429x; 3.1429x over previous
//
#include <hip/hip_runtime.h>

#define NN 160      // nodes
#define BB 128      // batch
#define HH 256      // hidden
#define EE 5120     // edges
#define ST 128      // state dim
#define AC 32       // action dim
#define HALF 128    // HH/2

typedef __attribute__((ext_vector_type(8))) short short8;
typedef __attribute__((ext_vector_type(4))) short bf16x4;
typedef __attribute__((ext_vector_type(4))) float f32x4;
typedef unsigned short us;

__device__ inline us f2b(float f) {
    unsigned u = __builtin_bit_cast(unsigned, f);
    unsigned r = (u + 0x7FFFu + ((u >> 16) & 1u)) >> 16;
    return (us)r;
}

// ---------- K1: graph rows + P row (int-exact) + weight transposes ----------
__global__ __launch_bounds__(256)
void k_pre(const int* __restrict__ ei, const float* __restrict__ W1,
           const float* __restrict__ W2, float* __restrict__ P,
           us* __restrict__ Mb, us* __restrict__ W1t, us* __restrict__ W2t)
{
    const int bx = blockIdx.x, tid = threadIdx.x;
    if (bx < NN) {
        __shared__ int crow[NN];
        __shared__ unsigned abit[NN * NN / 32];   // 3.2 KB
        __shared__ float invdeg;
        if (tid < NN) crow[tid] = 0;
        for (int i = tid; i < NN * NN / 32; i += 256) abit[i] = 0;
        __syncthreads();
        for (int e = tid; e < EE; e += 256) {
            int s = ei[e], d = ei[EE + e];
            int p = d * NN + s;
            atomicOr(&abit[p >> 5], 1u << (p & 31));
            if (d == bx) atomicAdd(&crow[s], 1);
        }
        if (tid < NN) {
            int p = tid * NN + tid;
            atomicOr(&abit[p >> 5], 1u << (p & 31));
        }
        __syncthreads();
        if (tid == 0) {
            int dg = 0;
            for (int j = 0; j < NN; j++) dg += crow[j];
            invdeg = 1.0f / (float)(dg < 1 ? 1 : dg);
        }
        __syncthreads();
        if (tid < NN) {
            int s = 0;
            for (int k = 0; k < NN; k++) {
                int p = k * NN + tid;
                if (abit[p >> 5] & (1u << (p & 31))) s += crow[k];
            }
            P[bx * NN + tid]  = (float)s * invdeg;
            Mb[bx * NN + tid] = f2b((float)crow[tid] * invdeg);
        }
    } else if (bx < NN + 160) {                   // W1t: 256x160
        int idx = (bx - NN) * 256 + tid;
        int n = idx / NN, k = idx - n * NN;
        W1t[idx] = f2b(W1[k * HH + n]);
    } else {                                      // W2t: 256x256
        int idx = (bx - NN - 160) * 256 + tid;
        int n = idx >> 8, k = idx & 255;
        W2t[idx] = f2b(W2[k * HH + n]);
    }
}

// ---------- K2: whole per-batch pipeline, one block per batch, 512 thr ----------
// GEMM1': D[i][h] = sum_j Y[i][j]*W1t[ho+h][j]    -> h1[h][i] (packed writes)
// GEMM2': D[h][i] = sum_k h1[h][k]*Mb[i][k]       -> t_lds[i][ho+h] (packed)
// GEMM3 : D[i][h'] = sum_h t[i][h]*W2t[h'][h]     -> relu+pool+head -> out
__global__ __launch_bounds__(512)
void k_mega(const float* __restrict__ P, const float* __restrict__ state,
            const float* __restrict__ action, const us* __restrict__ W1t,
            const float* __restrict__ b1, const us* __restrict__ Mb,
            const us* __restrict__ W2t, const float* __restrict__ b2,
            const float* __restrict__ Wo, const float* __restrict__ bo,
            float* __restrict__ out)
{
    constexpr int KS = 40;    // staging K-stride (shorts)
    constexpr int H1S = 168;  // h1 row stride (2-way alias on b128 reads)
    constexpr int TS = 264;   // t row stride
    __shared__ float xb[NN];                           //   640 B
    __shared__ __align__(16) us t_lds[NN][TS];         // 84480 B
    __shared__ __align__(16) us h1[HALF][H1S];         // 43008 B
    __shared__ __align__(16) us stg[(NN + HALF) * KS]; // 23040 B => 151168 B
    us* sY  = stg;             // [NN][KS]   GEMM1 A (Y rows i)
    us* sW  = stg + NN * KS;   // [HALF][KS] GEMM1 Bt (W1t rows h)
    us* sM  = stg;             // [NN][KS]   GEMM2 Bt (Mb rows i)
    us* sW2 = stg;             // [HH][KS]   GEMM3 Bt (W2t rows h')
    float* pp2      = (float*)&h1[0][0];   // [8][HH]  (h1 dead by GEMM3 epi)
    float* partials = pp2 + 8 * HH;        // [4][ST]

    const int b = blockIdx.x;
    const int tid = threadIdx.x, lane = tid & 63, w = tid >> 6;  // 8 waves
    const int rl = lane & 15, kq = lane >> 4;
    const int rr = tid >> 2, cc = (tid & 3) * 8;   // staging chunk (all phases)

    if (tid < NN) xb[tid] = (tid < ST) ? state[b * ST + tid]
                                       : action[b * AC + (tid - ST)];
    __syncthreads();

    for (int hh = 0; hh < 2; hh++) {
        const int ho = hh * HALF;
        // ======== GEMM1': M=160(i), N=128(h-half), K=160(j) ========
        // waves 2(i)x4(h): WM=80 (5 frags), WN=32 (2 frags)
        {
            const int wr = w >> 2, wc = w & 3;
            // ---- stage step 0
            {
                *(short8*)&sW[rr * KS + cc] =
                    *(const short8*)&W1t[(size_t)(ho + rr) * NN + cc];
                const f32x4* p4 = (const f32x4*)&P[rr * NN + cc];
                f32x4 a0 = p4[0], a1 = p4[1];
                short8 y;
#pragma unroll
                for (int u = 0; u < 4; u++) {
                    y[u]     = (short)f2b(a0[u] * xb[cc + u]);
                    y[u + 4] = (short)f2b(a1[u] * xb[cc + 4 + u]);
                }
                *(short8*)&sY[rr * KS + cc] = y;
                if (tid < 128) {
                    const f32x4* q4 = (const f32x4*)&P[(128 + rr) * NN + cc];
                    f32x4 b0 = q4[0], b1v = q4[1];
                    short8 y2;
#pragma unroll
                    for (int u = 0; u < 4; u++) {
                        y2[u]     = (short)f2b(b0[u] * xb[cc + u]);
                        y2[u + 4] = (short)f2b(b1v[u] * xb[cc + 4 + u]);
                    }
                    *(short8*)&sY[(128 + rr) * KS + cc] = y2;
                }
            }
            __syncthreads();

            f32x4 acc[5][2];
#pragma unroll
            for (int f = 0; f < 5; f++)
#pragma unroll
                for (int j = 0; j < 2; j++) acc[f][j] = f32x4{0.f, 0.f, 0.f, 0.f};

            for (int k0 = 0; k0 < NN; k0 += 32) {
                const bool nxt = (k0 + 32) < NN;
                short8 nW;
                f32x4 a0, a1, b0, b1v;
                if (nxt) {   // T14: issue next-step loads before MFMA
                    nW = *(const short8*)&W1t[(size_t)(ho + rr) * NN + k0 + 32 + cc];
                    const f32x4* p4 = (const f32x4*)&P[rr * NN + k0 + 32 + cc];
                    a0 = p4[0]; a1 = p4[1];
                    if (tid < 128) {
                        const f32x4* q4 = (const f32x4*)&P[(128 + rr) * NN + k0 + 32 + cc];
                        b0 = q4[0]; b1v = q4[1];
                    }
                }
                short8 af[5], bf[2];
#pragma unroll
                for (int f = 0; f < 5; f++)
                    af[f] = *(const short8*)&sY[(wr * 80 + f * 16 + rl) * KS + kq * 8];
#pragma unroll
                for (int j = 0; j < 2; j++)
                    bf[j] = *(const short8*)&sW[(wc * 32 + j * 16 + rl) * KS + kq * 8];
#pragma unroll
                for (int f = 0; f < 5; f++)
#pragma unroll
                    for (int j = 0; j < 2; j++)
                        acc[f][j] = __builtin_amdgcn_mfma_f32_16x16x32_bf16(
                            af[f], bf[j], acc[f][j], 0, 0, 0);
                __syncthreads();
                if (nxt) {   // write-late into (now idle) buffer
                    *(short8*)&sW[rr * KS + cc] = nW;
                    short8 y;
#pragma unroll
                    for (int u = 0; u < 4; u++) {
                        y[u]     = (short)f2b(a0[u] * xb[k0 + 32 + cc + u]);
                        y[u + 4] = (short)f2b(a1[u] * xb[k0 + 32 + cc + 4 + u]);
                    }
                    *(short8*)&sY[rr * KS + cc] = y;
                    if (tid < 128) {
                        short8 y2;
#pragma unroll
                        for (int u = 0; u < 4; u++) {
                            y2[u]     = (short)f2b(b0[u] * xb[k0 + 32 + cc + u]);
                            y2[u + 4] = (short)f2b(b1v[u] * xb[k0 + 32 + cc + 4 + u]);
                        }
                        *(short8*)&sY[(128 + rr) * KS + cc] = y2;
                    }
                }
                __syncthreads();
            }
            // epilogue: D rows=i (4 consec per lane), col=h -> packed h1[h][i0..3]
#pragma unroll
            for (int f = 0; f < 5; f++) {
                int i0 = wr * 80 + f * 16 + kq * 4;
#pragma unroll
                for (int j = 0; j < 2; j++) {
                    int h = wc * 32 + j * 16 + rl;
                    float bias = b1[ho + h];
                    bf16x4 v;
#pragma unroll
                    for (int r = 0; r < 4; r++) {
                        float t = acc[f][j][r] + bias;
                        v[r] = (short)f2b(t > 0.f ? t : 0.f);
                    }
                    *(bf16x4*)&h1[h][i0] = v;
                }
            }
        }
        __syncthreads();

        // ======== GEMM2': M=128(h-half), N=160(i), K=160(k) ========
        // waves 4(h)x2(i): WM=32 (2 frags), WN=80 (5 frags); A from LDS h1
        {
            const int wr = w >> 1, wc = w & 1;
            // stage step 0 (Mb rows)
            *(short8*)&sM[rr * KS + cc] = *(const short8*)&Mb[(size_t)rr * NN + cc];
            if (tid < 128)
                *(short8*)&sM[(128 + rr) * KS + cc] =
                    *(const short8*)&Mb[(size_t)(128 + rr) * NN + cc];
            __syncthreads();

            f32x4 acc[2][5];
#pragma unroll
            for (int f = 0; f < 2; f++)
#pragma unroll
                for (int j = 0; j < 5; j++) acc[f][j] = f32x4{0.f, 0.f, 0.f, 0.f};

            for (int k0 = 0; k0 < NN; k0 += 32) {
                const bool nxt = (k0 + 32) < NN;
                short8 nM0, nM1;
                if (nxt) {
                    nM0 = *(const short8*)&Mb[(size_t)rr * NN + k0 + 32 + cc];
                    if (tid < 128)
                        nM1 = *(const short8*)&Mb[(size_t)(128 + rr) * NN + k0 + 32 + cc];
                }
                short8 af[2], bf[5];
#pragma unroll
                for (int f = 0; f < 2; f++)
                    af[f] = *(const short8*)&h1[wr * 32 + f * 16 + rl][k0 + kq * 8];
#pragma unroll
                for (int j = 0; j < 5; j++)
                    bf[j] = *(const short8*)&sM[(wc * 80 + j * 16 + rl) * KS + kq * 8];
#pragma unroll
                for (int f = 0; f < 2; f++)
#pragma unroll
                    for (int j = 0; j < 5; j++)
                        acc[f][j] = __builtin_amdgcn_mfma_f32_16x16x32_bf16(
                            af[f], bf[j], acc[f][j], 0, 0, 0);
                __syncthreads();
                if (nxt) {
                    *(short8*)&sM[rr * KS + cc] = nM0;
                    if (tid < 128)
                        *(short8*)&sM[(128 + rr) * KS + cc] = nM1;
                }
                __syncthreads();
            }
            // epilogue: D rows=h (4 consec per lane), col=i -> packed t_lds[i][h0..3]
#pragma unroll
            for (int f = 0; f < 2; f++) {
                int h0 = wr * 32 + f * 16 + kq * 4;
#pragma unroll
                for (int j = 0; j < 5; j++) {
                    int i = wc * 80 + j * 16 + rl;
                    bf16x4 v;
#pragma unroll
                    for (int r = 0; r < 4; r++)
                        v[r] = (short)f2b(acc[f][j][r]);
                    *(bf16x4*)&t_lds[i][ho + h0] = v;
                }
            }
        }
        __syncthreads();
    }

    // ======== GEMM3: M=160(i), N=256(h'), K=256(h). A from LDS t ========
    // waves 2(i)x4(h'): WM=80 (5 frags), WN=64 (4 frags)
    {
        const int wr = w >> 2, wc = w & 3;
        // stage step 0 (W2t rows, 2 chunks/thread)
        *(short8*)&sW2[rr * KS + cc] = *(const short8*)&W2t[(size_t)rr * HH + cc];
        *(short8*)&sW2[(128 + rr) * KS + cc] =
            *(const short8*)&W2t[(size_t)(128 + rr) * HH + cc];
        __syncthreads();

        f32x4 acc[5][4];
#pragma unroll
        for (int f = 0; f < 5; f++)
#pragma unroll
            for (int j = 0; j < 4; j++) acc[f][j] = f32x4{0.f, 0.f, 0.f, 0.f};

        for (int k0 = 0; k0 < HH; k0 += 32) {
            const bool nxt = (k0 + 32) < HH;
            short8 nA, nB;
            if (nxt) {
                nA = *(const short8*)&W2t[(size_t)rr * HH + k0 + 32 + cc];
                nB = *(const short8*)&W2t[(size_t)(128 + rr) * HH + k0 + 32 + cc];
            }
            short8 af[5], bf[4];
#pragma unroll
            for (int f = 0; f < 5; f++)
                af[f] = *(const short8*)&t_lds[wr * 80 + f * 16 + rl][k0 + kq * 8];
#pragma unroll
            for (int j = 0; j < 4; j++)
                bf[j] = *(const short8*)&sW2[(wc * 64 + j * 16 + rl) * KS + kq * 8];
#pragma unroll
            for (int f = 0; f < 5; f++)
#pragma unroll
                for (int j = 0; j < 4; j++)
                    acc[f][j] = __builtin_amdgcn_mfma_f32_16x16x32_bf16(
                        af[f], bf[j], acc[f][j], 0, 0, 0);
            __syncthreads();
            if (nxt) {
                *(short8*)&sW2[rr * KS + cc] = nA;
                *(short8*)&sW2[(128 + rr) * KS + cc] = nB;
            }
            __syncthreads();
        }
        // epilogue: bias+relu, in-lane sum over 20 i-rows, slotted store
        const int slot = wr * 4 + kq;
#pragma unroll
        for (int j = 0; j < 4; j++) {
            int h = wc * 64 + j * 16 + rl;
            float bias = b2[h];
            float s = 0.f;
#pragma unroll
            for (int f = 0; f < 5; f++)
#pragma unroll
                for (int r = 0; r < 4; r++) {
                    float v = acc[f][j][r] + bias;
                    s += v > 0.f ? v : 0.f;
                }
            pp2[slot * HH + h] = s;
        }
    }
    __syncthreads();
    // head: out[b] = (pool/NN)@Wo + bo + state[b]   (deterministic, no atomics)
    {
        const int q = tid >> 7, s = tid & 127;
        float part = 0.f;
        for (int k = q * 64; k < q * 64 + 64; k++) {
            float pk = pp2[0 * HH + k] + pp2[1 * HH + k] + pp2[2 * HH + k] +
                       pp2[3 * HH + k] + pp2[4 * HH + k] + pp2[5 * HH + k] +
                       pp2[6 * HH + k] + pp2[7 * HH + k];
            part += pk * Wo[k * ST + s];
        }
        partials[q * ST + s] = part;
        __syncthreads();
        if (tid < ST) {
            float acc_o = (partials[0 * ST + tid] + partials[1 * ST + tid] +
                           partials[2 * ST + tid] + partials[3 * ST + tid]) * (1.0f / NN);
            out[b * ST + tid] = acc_o + bo[tid] + state[b * ST + tid];
        }
    }
}

extern "C" void kernel_launch(void* const* d_in, const int* in_sizes, int n_in,
                              void* d_out, int out_size, void* d_ws, size_t ws_size,
                              hipStream_t stream) {
    const float* state  = (const float*)d_in[0];
    const float* action = (const float*)d_in[1];
    const int*   ei     = (const int*)d_in[2];
    const float* W1     = (const float*)d_in[3];
    const float* b1     = (const float*)d_in[4];
    const float* W2     = (const float*)d_in[5];
    const float* b2     = (const float*)d_in[6];
    const float* Wo     = (const float*)d_in[7];
    const float* bo     = (const float*)d_in[8];
    float* out = (float*)d_out;

    char* ws = (char*)d_ws;
    size_t off = 0;
    auto alloc = [&](size_t bytes) {
        void* p = ws + off;
        off += (bytes + 255) & ~(size_t)255;
        return p;
    };
    float* P   = (float*)alloc(NN * NN * 4);
    us* Mb  = (us*)alloc(NN * NN * 2);
    us* W1t = (us*)alloc((size_t)HH * NN * 2);
    us* W2t = (us*)alloc((size_t)HH * HH * 2);

    k_pre<<<NN + 160 + 256, 256, 0, stream>>>(ei, W1, W2, P, Mb, W1t, W2t);
    k_mega<<<BB, 512, 0, stream>>>(P, state, action, W1t, b1, Mb, W2t, b2,
                                   Wo, bo, out);
}

// Round 10
// 41.411 us; speedup vs baseline: 3.3150x; 1.0548x over previous
//
#include <hip/hip_runtime.h>

#define NN 160      // nodes
#define BB 128      // batch
#define HH 256      // hidden
#define EE 5120     // edges
#define ST 128      // state dim
#define AC 32       // action dim
#define HALF 128    // HH/2

typedef __attribute__((ext_vector_type(8))) short short8;
typedef __attribute__((ext_vector_type(4))) short bf16x4;
typedef __attribute__((ext_vector_type(4))) float f32x4;
typedef unsigned short us;

__device__ inline us f2b(float f) {
    unsigned u = __builtin_bit_cast(unsigned, f);
    unsigned r = (u + 0x7FFFu + ((u >> 16) & 1u)) >> 16;
    return (us)r;
}
__device__ inline float b2f(us h) {
    return __builtin_bit_cast(float, (unsigned)h << 16);
}

// ---------- K1: graph rows + Pb row (int-exact, bf16) + weight transposes ----------
__global__ __launch_bounds__(256)
void k_pre(const int* __restrict__ ei, const float* __restrict__ W1,
           const float* __restrict__ W2, us* __restrict__ Pb,
           us* __restrict__ Mb, us* __restrict__ W1t, us* __restrict__ W2t)
{
    const int bx = blockIdx.x, tid = threadIdx.x;
    if (bx < NN) {
        __shared__ int crow[NN];
        __shared__ unsigned abit[NN * NN / 32];   // 3.2 KB
        __shared__ float invdeg;
        if (tid < NN) crow[tid] = 0;
        for (int i = tid; i < NN * NN / 32; i += 256) abit[i] = 0;
        __syncthreads();
        for (int e = tid; e < EE; e += 256) {
            int s = ei[e], d = ei[EE + e];
            int p = d * NN + s;
            atomicOr(&abit[p >> 5], 1u << (p & 31));
            if (d == bx) atomicAdd(&crow[s], 1);
        }
        if (tid < NN) {
            int p = tid * NN + tid;
            atomicOr(&abit[p >> 5], 1u << (p & 31));
        }
        __syncthreads();
        if (tid == 0) {
            int dg = 0;
            for (int j = 0; j < NN; j++) dg += crow[j];
            invdeg = 1.0f / (float)(dg < 1 ? 1 : dg);
        }
        __syncthreads();
        if (tid < NN) {
            int s = 0;
            for (int k = 0; k < NN; k++) {
                int p = k * NN + tid;
                if (abit[p >> 5] & (1u << (p & 31))) s += crow[k];
            }
            Pb[bx * NN + tid] = f2b((float)s * invdeg);
            Mb[bx * NN + tid] = f2b((float)crow[tid] * invdeg);
        }
    } else if (bx < NN + 160) {                   // W1t: 256x160
        int idx = (bx - NN) * 256 + tid;
        int n = idx / NN, k = idx - n * NN;
        W1t[idx] = f2b(W1[k * HH + n]);
    } else {                                      // W2t: 256x256
        int idx = (bx - NN - 160) * 256 + tid;
        int n = idx >> 8, k = idx & 255;
        W2t[idx] = f2b(W2[k * HH + n]);
    }
}

// ---------- K2: per-batch pipeline, 1024 threads (16 waves = 4/SIMD) ----------
// G1: D[i][h] = sum_j Y[i][j]*W1t[ho+h][j]  -> h1[h][i] packed
// G2: D[h][i] = sum_k h1[h][k]*Mb[i][k]     -> t_res[i][ho+h] packed
// G3: D[i][h'] = sum_h t[i][h]*W2t[h'][h]   -> relu+pool+head -> out
__global__ __launch_bounds__(1024, 4)
void k_mega(const us* __restrict__ Pb, const float* __restrict__ state,
            const float* __restrict__ action, const us* __restrict__ W1t,
            const float* __restrict__ b1, const us* __restrict__ Mb,
            const us* __restrict__ W2t, const float* __restrict__ b2,
            const float* __restrict__ Wo, const float* __restrict__ bo,
            float* __restrict__ out)
{
    constexpr int KS = 40;    // staging K-stride (shorts)
    constexpr int H1S = 168;  // h1 row stride
    constexpr int TS = 264;   // t row stride
    __shared__ float xb[NN];                           //   640 B
    __shared__ __align__(16) us t_res[NN][TS];         // 84480 B
    __shared__ __align__(16) us h1[HALF][H1S];         // 43008 B
    __shared__ __align__(16) us stg[(NN + HALF) * KS]; // 23040 B => 151168 B
    us* sY  = stg;             // [NN][KS]   G1 A (Y rows i)
    us* sW  = stg + NN * KS;   // [HALF][KS] G1 B (W1t rows h)
    us* sM  = stg;             // [NN][KS]   G2 B (Mb rows i)
    us* sW2 = stg;             // [HH][KS]   G3 B (W2t rows h')
    float* pp2      = (float*)&h1[0][0];   // [8][HH]  (h1 dead by G3 epi)
    float* partials = pp2 + 8 * HH;        // [8][ST]

    const int b = blockIdx.x;
    const int tid = threadIdx.x, lane = tid & 63, w = tid >> 6;  // 16 waves
    const int rl = lane & 15, kq = lane >> 4;

    // staging chunk maps
    const bool isY = tid < 640;                 // Y/Mb chunks (160 rows x 4)
    const int rY = tid >> 2, cY = (tid & 3) * 8;          // valid when isY
    const int hW = (tid - 640) >> 2, cW = ((tid - 640) & 3) * 8;  // W1t chunk
    const int hW2 = 96 + (tid >> 2), cW2 = (tid & 3) * 8; // 2nd W1t chunk (tid<128)
    const int r3 = tid >> 2, c3 = (tid & 3) * 8;          // W2t chunk (all)

    if (tid < NN) xb[tid] = (tid < ST) ? state[b * ST + tid]
                                       : action[b * AC + (tid - ST)];
    __syncthreads();

    for (int hh = 0; hh < 2; hh++) {
        const int ho = hh * HALF;
        // ======== G1: [160 i x 128 h], K=160. waves 2(i) x 8(h) ========
        {
            const int wr = w >> 3, wc = w & 7;
            // stage step 0
            {
                short8 a8, b8;
                if (isY) a8 = *(const short8*)&Pb[rY * NN + cY];
                else     a8 = *(const short8*)&W1t[(size_t)(ho + hW) * NN + cW];
                if (tid < 128)
                    b8 = *(const short8*)&W1t[(size_t)(ho + hW2) * NN + cW2];
                if (isY) {
                    short8 y;
#pragma unroll
                    for (int u = 0; u < 8; u++)
                        y[u] = (short)f2b(b2f((us)a8[u]) * xb[cY + u]);
                    *(short8*)&sY[rY * KS + cY] = y;
                } else {
                    *(short8*)&sW[hW * KS + cW] = a8;
                }
                if (tid < 128) *(short8*)&sW[hW2 * KS + cW2] = b8;
            }
            __syncthreads();

            f32x4 acc[5];
#pragma unroll
            for (int f = 0; f < 5; f++) acc[f] = f32x4{0.f, 0.f, 0.f, 0.f};

            for (int k0 = 0; k0 < NN; k0 += 32) {
                const bool nxt = (k0 + 32) < NN;
                short8 a8, b8;
                if (nxt) {   // issue next-step loads before MFMA
                    if (isY) a8 = *(const short8*)&Pb[rY * NN + k0 + 32 + cY];
                    else     a8 = *(const short8*)&W1t[(size_t)(ho + hW) * NN + k0 + 32 + cW];
                    if (tid < 128)
                        b8 = *(const short8*)&W1t[(size_t)(ho + hW2) * NN + k0 + 32 + cW2];
                }
                short8 af[5], bf;
#pragma unroll
                for (int f = 0; f < 5; f++)
                    af[f] = *(const short8*)&sY[(wr * 80 + f * 16 + rl) * KS + kq * 8];
                bf = *(const short8*)&sW[(wc * 16 + rl) * KS + kq * 8];
#pragma unroll
                for (int f = 0; f < 5; f++)
                    acc[f] = __builtin_amdgcn_mfma_f32_16x16x32_bf16(
                        af[f], bf, acc[f], 0, 0, 0);
                __syncthreads();
                if (nxt) {   // write-late
                    if (isY) {
                        short8 y;
#pragma unroll
                        for (int u = 0; u < 8; u++)
                            y[u] = (short)f2b(b2f((us)a8[u]) * xb[k0 + 32 + cY + u]);
                        *(short8*)&sY[rY * KS + cY] = y;
                    } else {
                        *(short8*)&sW[hW * KS + cW] = a8;
                    }
                    if (tid < 128) *(short8*)&sW[hW2 * KS + cW2] = b8;
                }
                __syncthreads();
            }
            // epilogue: D rows=i (4 consec), col=h -> packed h1[h][i0..3]
            {
                int h = wc * 16 + rl;
                float bias = b1[ho + h];
#pragma unroll
                for (int f = 0; f < 5; f++) {
                    int i0 = wr * 80 + f * 16 + kq * 4;
                    bf16x4 v;
#pragma unroll
                    for (int r = 0; r < 4; r++) {
                        float t = acc[f][r] + bias;
                        v[r] = (short)f2b(t > 0.f ? t : 0.f);
                    }
                    *(bf16x4*)&h1[h][i0] = v;
                }
            }
        }
        __syncthreads();

        // ======== G2: [128 h x 160 i], K=160. waves 8(h) x 2(i) ========
        {
            const int hg = w >> 1, ig = w & 1;
            // stage step 0 (Mb rows)
            if (isY)
                *(short8*)&sM[rY * KS + cY] = *(const short8*)&Mb[(size_t)rY * NN + cY];
            __syncthreads();

            f32x4 acc[5];
#pragma unroll
            for (int j = 0; j < 5; j++) acc[j] = f32x4{0.f, 0.f, 0.f, 0.f};

            for (int k0 = 0; k0 < NN; k0 += 32) {
                const bool nxt = (k0 + 32) < NN;
                short8 m8;
                if (nxt && isY)
                    m8 = *(const short8*)&Mb[(size_t)rY * NN + k0 + 32 + cY];
                short8 af, bf[5];
                af = *(const short8*)&h1[hg * 16 + rl][k0 + kq * 8];
#pragma unroll
                for (int j = 0; j < 5; j++)
                    bf[j] = *(const short8*)&sM[(ig * 80 + j * 16 + rl) * KS + kq * 8];
#pragma unroll
                for (int j = 0; j < 5; j++)
                    acc[j] = __builtin_amdgcn_mfma_f32_16x16x32_bf16(
                        af, bf[j], acc[j], 0, 0, 0);
                __syncthreads();
                if (nxt && isY) *(short8*)&sM[rY * KS + cY] = m8;
                __syncthreads();
            }
            // epilogue: D rows=h (4 consec), col=i -> packed t_res[i][ho+h0..3]
            {
                int h0 = hg * 16 + kq * 4;
#pragma unroll
                for (int j = 0; j < 5; j++) {
                    int i = ig * 80 + j * 16 + rl;
                    bf16x4 v;
#pragma unroll
                    for (int r = 0; r < 4; r++)
                        v[r] = (short)f2b(acc[j][r]);
                    *(bf16x4*)&t_res[i][ho + h0] = v;
                }
            }
        }
        __syncthreads();
    }

    // ======== G3: [160 i x 256 h'], K=256. waves 2(i) x 8(h') ========
    {
        const int wr = w >> 3, wc = w & 7;
        // stage step 0 (W2t rows, 1 chunk/thread)
        *(short8*)&sW2[r3 * KS + c3] = *(const short8*)&W2t[(size_t)r3 * HH + c3];
        __syncthreads();

        f32x4 acc[5][2];
#pragma unroll
        for (int f = 0; f < 5; f++)
#pragma unroll
            for (int j = 0; j < 2; j++) acc[f][j] = f32x4{0.f, 0.f, 0.f, 0.f};

        for (int k0 = 0; k0 < HH; k0 += 32) {
            const bool nxt = (k0 + 32) < HH;
            short8 w8;
            if (nxt)
                w8 = *(const short8*)&W2t[(size_t)r3 * HH + k0 + 32 + c3];
            short8 af[5], bf[2];
#pragma unroll
            for (int f = 0; f < 5; f++)
                af[f] = *(const short8*)&t_res[wr * 80 + f * 16 + rl][k0 + kq * 8];
#pragma unroll
            for (int j = 0; j < 2; j++)
                bf[j] = *(const short8*)&sW2[(wc * 32 + j * 16 + rl) * KS + kq * 8];
#pragma unroll
            for (int f = 0; f < 5; f++)
#pragma unroll
                for (int j = 0; j < 2; j++)
                    acc[f][j] = __builtin_amdgcn_mfma_f32_16x16x32_bf16(
                        af[f], bf[j], acc[f][j], 0, 0, 0);
            __syncthreads();
            if (nxt) *(short8*)&sW2[r3 * KS + c3] = w8;
            __syncthreads();
        }
        // epilogue: bias+relu, in-lane sum over 20 i-rows, slotted store
        const int slot = wr * 4 + kq;
#pragma unroll
        for (int j = 0; j < 2; j++) {
            int h = wc * 32 + j * 16 + rl;
            float bias = b2[h];
            float s = 0.f;
#pragma unroll
            for (int f = 0; f < 5; f++)
#pragma unroll
                for (int r = 0; r < 4; r++) {
                    float v = acc[f][j][r] + bias;
                    s += v > 0.f ? v : 0.f;
                }
            pp2[slot * HH + h] = s;
        }
    }
    __syncthreads();
    // head: out[b] = (pool/NN)@Wo + bo + state[b]   (deterministic)
    {
        const int q = tid >> 7, s = tid & 127;   // 8 k-quarters of 32
        float part = 0.f;
        for (int k = q * 32; k < q * 32 + 32; k++) {
            float pk = pp2[0 * HH + k] + pp2[1 * HH + k] + pp2[2 * HH + k] +
                       pp2[3 * HH + k] + pp2[4 * HH + k] + pp2[5 * HH + k] +
                       pp2[6 * HH + k] + pp2[7 * HH + k];
            part += pk * Wo[k * ST + s];
        }
        partials[q * ST + s] = part;
        __syncthreads();
        if (tid < ST) {
            float acc_o = 0.f;
#pragma unroll
            for (int qq = 0; qq < 8; qq++) acc_o += partials[qq * ST + tid];
            out[b * ST + tid] = acc_o * (1.0f / NN) + bo[tid] + state[b * ST + tid];
        }
    }
}

extern "C" void kernel_launch(void* const* d_in, const int* in_sizes, int n_in,
                              void* d_out, int out_size, void* d_ws, size_t ws_size,
                              hipStream_t stream) {
    const float* state  = (const float*)d_in[0];
    const float* action = (const float*)d_in[1];
    const int*   ei     = (const int*)d_in[2];
    const float* W1     = (const float*)d_in[3];
    const float* b1     = (const float*)d_in[4];
    const float* W2     = (const float*)d_in[5];
    const float* b2     = (const float*)d_in[6];
    const float* Wo     = (const float*)d_in[7];
    const float* bo     = (const float*)d_in[8];
    float* out = (float*)d_out;

    char* ws = (char*)d_ws;
    size_t off = 0;
    auto alloc = [&](size_t bytes) {
        void* p = ws + off;
        off += (bytes + 255) & ~(size_t)255;
        return p;
    };
    us* Pb  = (us*)alloc(NN * NN * 2);
    us* Mb  = (us*)alloc(NN * NN * 2);
    us* W1t = (us*)alloc((size_t)HH * NN * 2);
    us* W2t = (us*)alloc((size_t)HH * HH * 2);

    k_pre<<<NN + 160 + 256, 256, 0, stream>>>(ei, W1, W2, Pb, Mb, W1t, W2t);
    k_mega<<<BB, 1024, 0, stream>>>(Pb, state, action, W1t, b1, Mb, W2t, b2,
                                    Wo, bo, out);
}

// Round 11
// 40.060 us; speedup vs baseline: 3.4268x; 1.0337x over previous
//
#include <hip/hip_runtime.h>

#define NN 160      // nodes
#define BB 128      // batch
#define HH 256      // hidden
#define EE 5120     // edges
#define ST 128      // state dim
#define AC 32       // action dim
#define HALF 128    // HH/2

typedef __attribute__((ext_vector_type(8))) short short8;
typedef __attribute__((ext_vector_type(4))) short bf16x4;
typedef __attribute__((ext_vector_type(4))) float f32x4;
typedef unsigned short us;

__device__ inline us f2b(float f) {
    unsigned u = __builtin_bit_cast(unsigned, f);
    unsigned r = (u + 0x7FFFu + ((u >> 16) & 1u)) >> 16;
    return (us)r;
}
__device__ inline float b2f(us h) {
    return __builtin_bit_cast(float, (unsigned)h << 16);
}

// ---------- K1: graph rows + Pb row (int-exact, bf16) + weight transposes ----------
__global__ __launch_bounds__(256)
void k_pre(const int* __restrict__ ei, const float* __restrict__ W1,
           const float* __restrict__ W2, us* __restrict__ Pb,
           us* __restrict__ Mb, us* __restrict__ W1t, us* __restrict__ W2t)
{
    const int bx = blockIdx.x, tid = threadIdx.x;
    if (bx < NN) {
        __shared__ int crow[NN];
        __shared__ unsigned abit[NN * NN / 32];   // 3.2 KB
        __shared__ float invdeg;
        if (tid < NN) crow[tid] = 0;
        for (int i = tid; i < NN * NN / 32; i += 256) abit[i] = 0;
        __syncthreads();
        for (int e = tid; e < EE; e += 256) {
            int s = ei[e], d = ei[EE + e];
            int p = d * NN + s;
            atomicOr(&abit[p >> 5], 1u << (p & 31));
            if (d == bx) atomicAdd(&crow[s], 1);
        }
        if (tid < NN) {
            int p = tid * NN + tid;
            atomicOr(&abit[p >> 5], 1u << (p & 31));
        }
        __syncthreads();
        if (tid == 0) {
            int dg = 0;
            for (int j = 0; j < NN; j++) dg += crow[j];
            invdeg = 1.0f / (float)(dg < 1 ? 1 : dg);
        }
        __syncthreads();
        if (tid < NN) {
            int s = 0;
            for (int k = 0; k < NN; k++) {
                int p = k * NN + tid;
                if (abit[p >> 5] & (1u << (p & 31))) s += crow[k];
            }
            Pb[bx * NN + tid] = f2b((float)s * invdeg);
            Mb[bx * NN + tid] = f2b((float)crow[tid] * invdeg);
        }
    } else if (bx < NN + 160) {                   // W1t: 256x160
        int idx = (bx - NN) * 256 + tid;
        int n = idx / NN, k = idx - n * NN;
        W1t[idx] = f2b(W1[k * HH + n]);
    } else {                                      // W2t: 256x256
        int idx = (bx - NN - 160) * 256 + tid;
        int n = idx >> 8, k = idx & 255;
        W2t[idx] = f2b(W2[k * HH + n]);
    }
}

// ---------- K2: per-batch pipeline, operand-resident, barrier-light ----------
// per hh half: G1 (Y,W1t resident): D[i][h] -> h1[h][i];
//              G2 (h1,Mb resident): D[h][i] -> t[i][h] (RC);
//              G3-partial (t + W2t K-chunks dbuf): acc3 += t·W2t^T over this half's K
// then: relu+pool+head from register acc3.
__global__ __launch_bounds__(1024, 4)
void k_mega(const us* __restrict__ Pb, const float* __restrict__ state,
            const float* __restrict__ action, const us* __restrict__ W1t,
            const float* __restrict__ b1, const us* __restrict__ Mb,
            const us* __restrict__ W2t, const float* __restrict__ b2,
            const float* __restrict__ Wo, const float* __restrict__ bo,
            float* __restrict__ out)
{
    constexpr int SA = 168;   // RA row stride (shorts): 336 B, 16B-aligned, bank-spread
    constexpr int SB = 168;   // RB row stride
    constexpr int SC = 136;   // RC row stride: 272 B
    constexpr int SD = 40;    // RD row stride: 80 B
    __shared__ __align__(16) us RA[160 * SA];     // 53760 B : Y / Mb / W2t-dbuf(RD)
    __shared__ __align__(16) us RB[128 * SB];     // 43008 B : W1t / h1 / pp2+partials
    __shared__ __align__(16) us RC[160 * SC];     // 43520 B : t half      => 140288 B
    __shared__ float xb[NN];
    us* RD = RA;                                  // [2][256*SD] = 40960 B
    float* pp2 = (float*)RB;                      // [8][HH]
    float* partials = pp2 + 8 * HH;               // [8][ST]

    const int b = blockIdx.x;
    const int tid = threadIdx.x, lane = tid & 63, w = tid >> 6;  // 16 waves
    const int rl = lane & 15, kq = lane >> 4;
    const int wr = w >> 3, wc = w & 7;     // G1/G3 tiling: 2(i) x 8(h)
    const int hg = w >> 1, ig = w & 1;     // G2 tiling: 8(h) x 2(i)
    const int rD = tid >> 2, cD = (tid & 3) * 8;  // W2t chunk map (1024 = 256x4)

    if (tid < NN) xb[tid] = (tid < ST) ? state[b * ST + tid]
                                       : action[b * AC + (tid - ST)];
    __syncthreads();

    f32x4 acc3[5][2];
#pragma unroll
    for (int f = 0; f < 5; f++)
#pragma unroll
        for (int j = 0; j < 2; j++) acc3[f][j] = f32x4{0.f, 0.f, 0.f, 0.f};

    for (int hh = 0; hh < 2; hh++) {
        const int ho = hh * HALF;
        // ---- stage: Y (3200 chunks) -> RA, W1t-half (2560) -> RB
        for (int c = tid; c < 3200; c += 1024) {
            int r = c / 20, col = (c - r * 20) * 8;
            short8 p = *(const short8*)&Pb[r * NN + col];
            short8 y;
#pragma unroll
            for (int u = 0; u < 8; u++)
                y[u] = (short)f2b(b2f((us)p[u]) * xb[col + u]);
            *(short8*)&RA[r * SA + col] = y;
        }
        for (int c = tid; c < 2560; c += 1024) {
            int r = c / 20, col = (c - r * 20) * 8;
            *(short8*)&RB[r * SB + col] =
                *(const short8*)&W1t[(size_t)(ho + r) * NN + col];
        }
        __syncthreads();

        // ---- G1: D[i][h], K=160, barrier-free (Y rows=A, W1t rows=Bt)
        {
            f32x4 acc1[5];
#pragma unroll
            for (int f = 0; f < 5; f++) acc1[f] = f32x4{0.f, 0.f, 0.f, 0.f};
            for (int k0 = 0; k0 < NN; k0 += 32) {
                short8 af[5], bv;
#pragma unroll
                for (int f = 0; f < 5; f++)
                    af[f] = *(const short8*)&RA[(wr * 80 + f * 16 + rl) * SA + k0 + kq * 8];
                bv = *(const short8*)&RB[(wc * 16 + rl) * SB + k0 + kq * 8];
#pragma unroll
                for (int f = 0; f < 5; f++)
                    acc1[f] = __builtin_amdgcn_mfma_f32_16x16x32_bf16(
                        af[f], bv, acc1[f], 0, 0, 0);
            }
            __syncthreads();   // all G1 reads of RA/RB complete
            // epi: h1[h][i] packed into RB (over dead W1t); stage Mb -> RA
            {
                int h = wc * 16 + rl;
                float bias = b1[ho + h];
#pragma unroll
                for (int f = 0; f < 5; f++) {
                    int i0 = wr * 80 + f * 16 + kq * 4;
                    bf16x4 v;
#pragma unroll
                    for (int r = 0; r < 4; r++) {
                        float t = acc1[f][r] + bias;
                        v[r] = (short)f2b(t > 0.f ? t : 0.f);
                    }
                    *(bf16x4*)&RB[h * SB + i0] = v;
                }
            }
            for (int c = tid; c < 3200; c += 1024) {
                int r = c / 20, col = (c - r * 20) * 8;
                *(short8*)&RA[r * SA + col] = *(const short8*)&Mb[r * NN + col];
            }
        }
        __syncthreads();

        // ---- G2: D[h][i], K=160, barrier-free (h1 rows=A, Mb rows=Bt)
        {
            f32x4 acc2[5];
#pragma unroll
            for (int j = 0; j < 5; j++) acc2[j] = f32x4{0.f, 0.f, 0.f, 0.f};
            for (int k0 = 0; k0 < NN; k0 += 32) {
                short8 a = *(const short8*)&RB[(hg * 16 + rl) * SB + k0 + kq * 8];
                short8 bfv[5];
#pragma unroll
                for (int j = 0; j < 5; j++)
                    bfv[j] = *(const short8*)&RA[(ig * 80 + j * 16 + rl) * SA + k0 + kq * 8];
#pragma unroll
                for (int j = 0; j < 5; j++)
                    acc2[j] = __builtin_amdgcn_mfma_f32_16x16x32_bf16(
                        a, bfv[j], acc2[j], 0, 0, 0);
            }
            __syncthreads();   // G2 reads done: RA free (Mb dead), RB free
            // epi: t[i][h0..h0+3] packed -> RC; stage W2t chunk0 -> RD buf0
            {
                int h0 = hg * 16 + kq * 4;
#pragma unroll
                for (int j = 0; j < 5; j++) {
                    int i = ig * 80 + j * 16 + rl;
                    bf16x4 v;
#pragma unroll
                    for (int r = 0; r < 4; r++)
                        v[r] = (short)f2b(acc2[j][r]);
                    *(bf16x4*)&RC[i * SC + h0] = v;
                }
            }
            *(short8*)&RD[rD * SD + cD] =
                *(const short8*)&W2t[(size_t)rD * HH + ho + cD];
        }
        __syncthreads();

        // ---- G3 partial: K=128 over this half, 4 steps, dbuf W2t (1 barrier/step)
        for (int kk = 0; kk < 4; kk++) {
            short8 nxt;
            if (kk < 3)   // T14: issue early
                nxt = *(const short8*)&W2t[(size_t)rD * HH + ho + (kk + 1) * 32 + cD];
            const int cur = (kk & 1) * (256 * SD);
            short8 af[5], bfv[2];
#pragma unroll
            for (int f = 0; f < 5; f++)
                af[f] = *(const short8*)&RC[(wr * 80 + f * 16 + rl) * SC + kk * 32 + kq * 8];
#pragma unroll
            for (int j = 0; j < 2; j++)
                bfv[j] = *(const short8*)&RD[cur + (wc * 32 + j * 16 + rl) * SD + kq * 8];
#pragma unroll
            for (int f = 0; f < 5; f++)
#pragma unroll
                for (int j = 0; j < 2; j++)
                    acc3[f][j] = __builtin_amdgcn_mfma_f32_16x16x32_bf16(
                        af[f], bfv[j], acc3[f][j], 0, 0, 0);
            if (kk < 3)   // write-late into the idle buffer
                *(short8*)&RD[(cur ^ (256 * SD)) + rD * SD + cD] = nxt;
            __syncthreads();
        }
    } // hh

    // ---- epilogue: bias+relu+pool (in-lane over 20 i-rows), slotted -> pp2
    {
        const int slot = wr * 4 + kq;
#pragma unroll
        for (int j = 0; j < 2; j++) {
            int h = wc * 32 + j * 16 + rl;
            float bias = b2[h];
            float s = 0.f;
#pragma unroll
            for (int f = 0; f < 5; f++)
#pragma unroll
                for (int r = 0; r < 4; r++) {
                    float v = acc3[f][j][r] + bias;
                    s += v > 0.f ? v : 0.f;
                }
            pp2[slot * HH + h] = s;
        }
    }
    __syncthreads();
    // ---- head: out[b] = (pool/NN)@Wo + bo + state[b]  (deterministic)
    {
        const int q = tid >> 7, s = tid & 127;   // 8 k-chunks of 32
        float part = 0.f;
        for (int k = q * 32; k < q * 32 + 32; k++) {
            float pk = pp2[0 * HH + k] + pp2[1 * HH + k] + pp2[2 * HH + k] +
                       pp2[3 * HH + k] + pp2[4 * HH + k] + pp2[5 * HH + k] +
                       pp2[6 * HH + k] + pp2[7 * HH + k];
            part += pk * Wo[k * ST + s];
        }
        partials[q * ST + s] = part;
        __syncthreads();
        if (tid < ST) {
            float acc_o = 0.f;
#pragma unroll
            for (int qq = 0; qq < 8; qq++) acc_o += partials[qq * ST + tid];
            out[b * ST + tid] = acc_o * (1.0f / NN) + bo[tid] + state[b * ST + tid];
        }
    }
}

extern "C" void kernel_launch(void* const* d_in, const int* in_sizes, int n_in,
                              void* d_out, int out_size, void* d_ws, size_t ws_size,
                              hipStream_t stream) {
    const float* state  = (const float*)d_in[0];
    const float* action = (const float*)d_in[1];
    const int*   ei     = (const int*)d_in[2];
    const float* W1     = (const float*)d_in[3];
    const float* b1     = (const float*)d_in[4];
    const float* W2     = (const float*)d_in[5];
    const float* b2     = (const float*)d_in[6];
    const float* Wo     = (const float*)d_in[7];
    const float* bo     = (const float*)d_in[8];
    float* out = (float*)d_out;

    char* ws = (char*)d_ws;
    size_t off = 0;
    auto alloc = [&](size_t bytes) {
        void* p = ws + off;
        off += (bytes + 255) & ~(size_t)255;
        return p;
    };
    us* Pb  = (us*)alloc(NN * NN * 2);
    us* Mb  = (us*)alloc(NN * NN * 2);
    us* W1t = (us*)alloc((size_t)HH * NN * 2);
    us* W2t = (us*)alloc((size_t)HH * HH * 2);

    k_pre<<<NN + 160 + 256, 256, 0, stream>>>(ei, W1, W2, Pb, Mb, W1t, W2t);
    k_mega<<<BB, 1024, 0, stream>>>(Pb, state, action, W1t, b1, Mb, W2t, b2,
                                    Wo, bo, out);
}

// Round 12
// 38.351 us; speedup vs baseline: 3.5795x; 1.0445x over previous
//
#include <hip/hip_runtime.h>

#define NN 160      // nodes
#define BB 128      // batch
#define HH 256      // hidden
#define EE 5120     // edges
#define ST 128      // state dim
#define AC 32       // action dim
#define IH 80       // i-half rows

typedef __attribute__((ext_vector_type(8))) short short8;
typedef __attribute__((ext_vector_type(4))) short bf16x4;
typedef unsigned short us;
typedef __attribute__((ext_vector_type(4))) float f32x4;

__device__ inline us f2b(float f) {
    unsigned u = __builtin_bit_cast(unsigned, f);
    unsigned r = (u + 0x7FFFu + ((u >> 16) & 1u)) >> 16;
    return (us)r;
}
__device__ inline float b2f(us h) {
    return __builtin_bit_cast(float, (unsigned)h << 16);
}

// ---------- K1: graph rows + Pb/Mb (int-exact) + weight transposes + out init ----------
__global__ __launch_bounds__(256)
void k_pre(const int* __restrict__ ei, const float* __restrict__ W1,
           const float* __restrict__ W2, const float* __restrict__ state,
           const float* __restrict__ bo, us* __restrict__ Pb,
           us* __restrict__ Mb, us* __restrict__ W1t, us* __restrict__ W2t,
           float* __restrict__ out)
{
    const int bx = blockIdx.x, tid = threadIdx.x;
    if (bx < NN) {
        __shared__ int crow[NN];
        __shared__ unsigned abit[NN * NN / 32];   // 3.2 KB
        __shared__ float invdeg;
        if (tid < NN) crow[tid] = 0;
        for (int i = tid; i < NN * NN / 32; i += 256) abit[i] = 0;
        __syncthreads();
        for (int e = tid; e < EE; e += 256) {
            int s = ei[e], d = ei[EE + e];
            int p = d * NN + s;
            atomicOr(&abit[p >> 5], 1u << (p & 31));
            if (d == bx) atomicAdd(&crow[s], 1);
        }
        if (tid < NN) {
            int p = tid * NN + tid;
            atomicOr(&abit[p >> 5], 1u << (p & 31));
        }
        __syncthreads();
        if (tid == 0) {
            int dg = 0;
            for (int j = 0; j < NN; j++) dg += crow[j];
            invdeg = 1.0f / (float)(dg < 1 ? 1 : dg);
        }
        __syncthreads();
        if (tid < NN) {
            int s = 0;
            for (int k = 0; k < NN; k++) {
                int p = k * NN + tid;
                if (abit[p >> 5] & (1u << (p & 31))) s += crow[k];
            }
            Pb[bx * NN + tid] = f2b((float)s * invdeg);
            Mb[bx * NN + tid] = f2b((float)crow[tid] * invdeg);
        }
    } else if (bx < NN + 160) {                   // W1t: 256x160
        int idx = (bx - NN) * 256 + tid;
        int n = idx / NN, k = idx - n * NN;
        W1t[idx] = f2b(W1[k * HH + n]);
    } else if (bx < NN + 160 + 256) {             // W2t: 256x256
        int idx = (bx - NN - 160) * 256 + tid;
        int n = idx >> 8, k = idx & 255;
        W2t[idx] = f2b(W2[k * HH + n]);
    } else {                                      // out init: 128x128
        int idx = (bx - NN - 160 - 256) * 256 + tid;
        out[idx] = state[idx] + bo[idx & 127];
    }
}

// ---------- K2: 256 blocks = (i-half, batch), 1024 threads (16 waves) ----------
// G1 (full, dup x2): h1[h][k-node] = relu(sum_j Y[k][j]*W1t[h][j] + b1[h])
// G2 (i-half):       t[i'][h] = sum_k Mb[i0+i'][k]*h1[h][k]
// G3 (i-half):       acc = t @ W2t^T; relu+bias -> pool -> head -> atomic out
__global__ __launch_bounds__(1024, 4)
void k_mega(const us* __restrict__ Pb, const float* __restrict__ state,
            const float* __restrict__ action, const us* __restrict__ W1t,
            const float* __restrict__ b1, const us* __restrict__ Mb,
            const us* __restrict__ W2t, const float* __restrict__ b2,
            const float* __restrict__ Wo, float* __restrict__ out)
{
    __shared__ __align__(16) us h1s[256 * 168];   // 86016 B : h1 / W2t-dbuf
    __shared__ __align__(16) us R1[34560];        // 69120 B : {Y,W1t} -> {Mb,t,pp}
    __shared__ float xb[NN];
    us* Ys  = R1;                 // [160][40]  (12.8 KB)
    us* W1s = R1 + 6400;          // [128][168] (43 KB)
    us* Mbs = R1;                 // [80][168]  (26.9 KB)
    us* ts  = R1 + 13440;         // [80][264]  (42.2 KB)
    us* W2s = h1s;                // [2][256][40] dbuf (2x20.5 KB)
    float* pp  = (float*)R1;          // [4][256]  (4 KB, over dead Mbs)
    float* pts = (float*)(R1 + 2048); // [8][128]  (4 KB)

    const int ihalf = blockIdx.x, b = blockIdx.y, i_base = ihalf * IH;
    const int tid = threadIdx.x, lane = tid & 63, w = tid >> 6;  // 16 waves
    const int rl = lane & 15, kq = lane >> 4;
    const int wr = w >> 3, wc = w & 7;            // G1 tiling 2(i) x 8(h)
    const int rY = tid >> 2, cY = (tid & 3) * 8;  // Y chunk (tid<640)
    const int rD = tid >> 2, cD = (tid & 3) * 8;  // W2t chunk (1024 = 256x4)

    if (tid < NN) xb[tid] = (tid < ST) ? state[b * ST + tid]
                                       : action[b * AC + (tid - ST)];
    __syncthreads();

    // ======== G1 (duplicated): per hh half of hidden dim ========
    for (int hh = 0; hh < 2; hh++) {
        // stage W1t half (resident) + Y step0 (streamed)
        for (int c = tid; c < 2560; c += 1024) {
            int r = c / 20, col = (c - r * 20) * 8;
            *(short8*)&W1s[r * 168 + col] =
                *(const short8*)&W1t[(size_t)(hh * 128 + r) * NN + col];
        }
        if (tid < 640) {
            short8 p = *(const short8*)&Pb[rY * NN + cY];
            short8 y;
#pragma unroll
            for (int u = 0; u < 8; u++)
                y[u] = (short)f2b(b2f((us)p[u]) * xb[cY + u]);
            *(short8*)&Ys[rY * 40 + cY] = y;
        }
        __syncthreads();

        f32x4 acc1[5];
#pragma unroll
        for (int f = 0; f < 5; f++) acc1[f] = f32x4{0.f, 0.f, 0.f, 0.f};

        for (int k0 = 0; k0 < NN; k0 += 32) {
            const bool nxt = (k0 + 32) < NN;
            short8 p;
            if (nxt && tid < 640)   // T14: issue early
                p = *(const short8*)&Pb[rY * NN + k0 + 32 + cY];
            short8 af[5], bv;
#pragma unroll
            for (int f = 0; f < 5; f++)
                af[f] = *(const short8*)&Ys[(wr * 80 + f * 16 + rl) * 40 + kq * 8];
            bv = *(const short8*)&W1s[(wc * 16 + rl) * 168 + k0 + kq * 8];
#pragma unroll
            for (int f = 0; f < 5; f++)
                acc1[f] = __builtin_amdgcn_mfma_f32_16x16x32_bf16(
                    af[f], bv, acc1[f], 0, 0, 0);
            __syncthreads();
            if (nxt && tid < 640) {   // write-late
                short8 y;
#pragma unroll
                for (int u = 0; u < 8; u++)
                    y[u] = (short)f2b(b2f((us)p[u]) * xb[k0 + 32 + cY + u]);
                *(short8*)&Ys[rY * 40 + cY] = y;
            }
            __syncthreads();
        }
        // epi: D[i][h]: reg-quad = 4 consecutive i -> packed h1s[h][i0..3]
        {
            int h = hh * 128 + wc * 16 + rl;
            float bias = b1[h];
#pragma unroll
            for (int f = 0; f < 5; f++) {
                int i0 = wr * 80 + f * 16 + kq * 4;
                bf16x4 v;
#pragma unroll
                for (int r = 0; r < 4; r++) {
                    float t = acc1[f][r] + bias;
                    v[r] = (short)f2b(t > 0.f ? t : 0.f);
                }
                *(bf16x4*)&h1s[h * 168 + i0] = v;
            }
        }
    }
    __syncthreads();   // G1 done: R1 free for Mbs/ts; h1s complete

    // ======== G2: D[h 256][i' 80], K=160(k). wave w -> h rows [16w,16w+16) ========
    {
        for (int c = tid; c < 1600; c += 1024) {
            int r = c / 20, col = (c - r * 20) * 8;
            *(short8*)&Mbs[r * 168 + col] =
                *(const short8*)&Mb[(size_t)(i_base + r) * NN + col];
        }
        __syncthreads();

        f32x4 acc2[5];
#pragma unroll
        for (int j = 0; j < 5; j++) acc2[j] = f32x4{0.f, 0.f, 0.f, 0.f};

        for (int k0 = 0; k0 < NN; k0 += 32) {    // barrier-free (both resident)
            short8 a = *(const short8*)&h1s[(w * 16 + rl) * 168 + k0 + kq * 8];
            short8 bfv[5];
#pragma unroll
            for (int j = 0; j < 5; j++)
                bfv[j] = *(const short8*)&Mbs[(j * 16 + rl) * 168 + k0 + kq * 8];
#pragma unroll
            for (int j = 0; j < 5; j++)
                acc2[j] = __builtin_amdgcn_mfma_f32_16x16x32_bf16(
                    a, bfv[j], acc2[j], 0, 0, 0);
        }
        __syncthreads();   // h1s reads done -> W2s overlay allowed
        // epi: D[h][i']: reg-quad = 4 consecutive h -> packed ts[i'][h0..3]
        {
            int h0 = w * 16 + kq * 4;
#pragma unroll
            for (int j = 0; j < 5; j++) {
                int ip = j * 16 + rl;
                bf16x4 v;
#pragma unroll
                for (int r = 0; r < 4; r++)
                    v[r] = (short)f2b(acc2[j][r]);
                *(bf16x4*)&ts[ip * 264 + h0] = v;
            }
        }
        // stage W2t step0 into dbuf (over dead h1s)
        *(short8*)&W2s[rD * 40 + cD] = *(const short8*)&W2t[(size_t)rD * HH + cD];
        __syncthreads();
    }

    // ======== G3: D[i' 80][h' 256], K=256(h). wave w -> h' cols [16w,16w+16) ========
    f32x4 acc3[5];
#pragma unroll
    for (int f = 0; f < 5; f++) acc3[f] = f32x4{0.f, 0.f, 0.f, 0.f};

    for (int kk = 0; kk < 8; kk++) {
        const int cur = (kk & 1) * 10240;
        short8 w8;
        if (kk < 7)   // T14: issue early
            w8 = *(const short8*)&W2t[(size_t)rD * HH + (kk + 1) * 32 + cD];
        short8 af[5], bv;
#pragma unroll
        for (int f = 0; f < 5; f++)
            af[f] = *(const short8*)&ts[(f * 16 + rl) * 264 + kk * 32 + kq * 8];
        bv = *(const short8*)&W2s[cur + (w * 16 + rl) * 40 + kq * 8];
#pragma unroll
        for (int f = 0; f < 5; f++)
            acc3[f] = __builtin_amdgcn_mfma_f32_16x16x32_bf16(
                af[f], bv, acc3[f], 0, 0, 0);
        if (kk < 7)   // write-late into idle buffer (prev step's reads barrier'd)
            *(short8*)&W2s[(cur ^ 10240) + rD * 40 + cD] = w8;
        __syncthreads();
    }

    // ---- epi: bias+relu, in-lane pool over 20 i'-rows, slotted by kq ----
    {
        int h = w * 16 + rl;
        float bias = b2[h];
        float s = 0.f;
#pragma unroll
        for (int f = 0; f < 5; f++)
#pragma unroll
            for (int r = 0; r < 4; r++) {
                float v = acc3[f][r] + bias;
                s += v > 0.f ? v : 0.f;
            }
        pp[kq * HH + h] = s;
    }
    __syncthreads();
    // ---- head partial: out[b][s] += (sum_h ph[h]*Wo[h][s]) / NN ----
    {
        const int q = tid >> 7, s2 = tid & 127;   // 8 h-chunks of 32
        float part = 0.f;
        for (int hx = q * 32; hx < q * 32 + 32; hx++) {
            float ph = pp[0 * HH + hx] + pp[1 * HH + hx] +
                       pp[2 * HH + hx] + pp[3 * HH + hx];
            part += ph * Wo[hx * ST + s2];
        }
        pts[q * ST + s2] = part;
        __syncthreads();
        if (tid < ST) {
            float o = 0.f;
#pragma unroll
            for (int qq = 0; qq < 8; qq++) o += pts[qq * ST + tid];
            atomicAdd(&out[b * ST + tid], o * (1.0f / NN));
        }
    }
}

extern "C" void kernel_launch(void* const* d_in, const int* in_sizes, int n_in,
                              void* d_out, int out_size, void* d_ws, size_t ws_size,
                              hipStream_t stream) {
    const float* state  = (const float*)d_in[0];
    const float* action = (const float*)d_in[1];
    const int*   ei     = (const int*)d_in[2];
    const float* W1     = (const float*)d_in[3];
    const float* b1     = (const float*)d_in[4];
    const float* W2     = (const float*)d_in[5];
    const float* b2     = (const float*)d_in[6];
    const float* Wo     = (const float*)d_in[7];
    const float* bo     = (const float*)d_in[8];
    float* out = (float*)d_out;

    char* ws = (char*)d_ws;
    size_t off = 0;
    auto alloc = [&](size_t bytes) {
        void* p = ws + off;
        off += (bytes + 255) & ~(size_t)255;
        return p;
    };
    us* Pb  = (us*)alloc(NN * NN * 2);
    us* Mb  = (us*)alloc(NN * NN * 2);
    us* W1t = (us*)alloc((size_t)HH * NN * 2);
    us* W2t = (us*)alloc((size_t)HH * HH * 2);

    // 160 graph rows + 160 W1t blocks + 256 W2t blocks + 64 out-init blocks
    k_pre<<<NN + 160 + 256 + 64, 256, 0, stream>>>(ei, W1, W2, state, bo,
                                                   Pb, Mb, W1t, W2t, out);
    {
        dim3 g(2, BB);   // (i-half, batch) = 256 blocks
        k_mega<<<g, 1024, 0, stream>>>(Pb, state, action, W1t, b1, Mb, W2t, b2,
                                       Wo, out);
    }
}